// Round 7
// baseline (143.424 us; speedup 1.0000x reference)
//
#include <hip/hip_runtime.h>
#include <hip/hip_bf16.h>
#include <math.h>

#define NN 8192
#define NFEAT 1433
#define NHID 64
#define NCLASS 7
#define CAP 96
#define QCAP 48           // per-quarter nonzero cap (mean ~8, Poisson tail safe)

#define KSPLIT 8
#define KCHUNK 192        // 8*192 = 1536 >= 1433; 6 k-steps of 32 per chunk
#define NB_GEMM 1024      // 128 tiles x 8 k-chunks
#define NB_BUILD 8192     // 1 row per block, 4 waves scan quarters

typedef float f32x4 __attribute__((ext_vector_type(4)));
typedef short bf16x8 __attribute__((ext_vector_type(8)));

__device__ __forceinline__ ushort f2bf(float f) {
    __hip_bfloat16 h = __float2bfloat16(f);
    return *reinterpret_cast<ushort*>(&h);
}

// ---------------------------------------------------------------------------
// Fused kernel. Grid = 9216 = 1024*9. b%9==0 -> GEMM role (1024 blocks);
// else build role (8192 blocks, one adjacency row per block).
// GEMM role: bf16 MFMA 16x16x32, 64x64 tile x 192-K chunk, W1 converted
// inline (k_prep eliminated). Build role: 4 waves scan quarters of the row
// with short 32-step ballot chains into LDS lists; stitch; one lane-parallel
// pass gathers P, computes sigmoid, writes cols/vals coalesced.
// ---------------------------------------------------------------------------
__global__ __launch_bounds__(256, 8) void k_fused(const float* __restrict__ adj,
                                                  const float* __restrict__ P,
                                                  const float* __restrict__ x,
                                                  const float* __restrict__ W1,
                                                  float* __restrict__ dinv,
                                                  int* __restrict__ cnt,
                                                  int* __restrict__ cols,
                                                  float* __restrict__ vals,
                                                  float* __restrict__ part) {
    __shared__ __align__(16) union SMem {
        struct { ushort xa[64][40]; ushort wt[64][40]; } g;          // GEMM tiles
        struct { int qbuf[4][QCAP]; int qcnt[4]; float dpart[4]; } bl; // build
    } sm;

    const int t  = threadIdx.x;
    const int b  = blockIdx.x;
    const int r9 = b % 9;
    const int q9 = b / 9;

    if (r9 == 0) {
        // ----------------- GEMM role (MFMA bf16) -----------------
        const int tile = q9 >> 3;        // 0..127
        const int ks   = q9 & 7;         // 0..7
        const int m0 = tile * 64;
        const int k_begin = ks * KCHUNK;
        const int k_end   = (k_begin + KCHUNK < NFEAT) ? k_begin + KCHUNK : NFEAT;
        const int l = t & 63;
        const int w = t >> 6;

        // x staging: thread -> (row sr, 8 consecutive k at sc8)
        const int sr  = t >> 2;          // 0..63
        const int sc8 = (t & 3) * 8;     // 0,8,16,24
        const float* xrow = x + (size_t)(m0 + sr) * NFEAT;
        // W staging: thread -> (col wc, 8 consecutive k at wk8); loads are
        // coalesced across lanes (consecutive c at fixed k).
        const int wc  = t & 63;
        const int wk8 = (t >> 6) * 8;
        // mfma fragment coords
        const int arow = w * 16 + (l & 15);
        const int kb   = (l >> 4) * 8;   // 0,8,16,24

        f32x4 acc[4];
        #pragma unroll
        for (int ct = 0; ct < 4; ++ct) acc[ct] = (f32x4){0.f, 0.f, 0.f, 0.f};

        for (int k0 = k_begin; k0 < k_end; k0 += 32) {
            uint4 xp;
            {
                ushort u[8];
                #pragma unroll
                for (int jj = 0; jj < 8; ++jj) {
                    int k = k0 + sc8 + jj;
                    u[jj] = f2bf((k < k_end) ? xrow[k] : 0.f);
                }
                xp.x = (unsigned)u[0] | ((unsigned)u[1] << 16);
                xp.y = (unsigned)u[2] | ((unsigned)u[3] << 16);
                xp.z = (unsigned)u[4] | ((unsigned)u[5] << 16);
                xp.w = (unsigned)u[6] | ((unsigned)u[7] << 16);
            }
            *(uint4*)(&sm.g.xa[sr][sc8]) = xp;
            uint4 wp;
            {
                ushort u[8];
                #pragma unroll
                for (int jj = 0; jj < 8; ++jj) {
                    int k = k0 + wk8 + jj;
                    u[jj] = f2bf((k < k_end) ? W1[(size_t)k * 64 + wc] : 0.f);
                }
                wp.x = (unsigned)u[0] | ((unsigned)u[1] << 16);
                wp.y = (unsigned)u[2] | ((unsigned)u[3] << 16);
                wp.z = (unsigned)u[4] | ((unsigned)u[5] << 16);
                wp.w = (unsigned)u[6] | ((unsigned)u[7] << 16);
            }
            *(uint4*)(&sm.g.wt[wc][wk8]) = wp;
            __syncthreads();

            bf16x8 af = *(const bf16x8*)(&sm.g.xa[arow][kb]);
            #pragma unroll
            for (int ct = 0; ct < 4; ++ct) {
                bf16x8 bfr = *(const bf16x8*)(&sm.g.wt[ct * 16 + (l & 15)][kb]);
                acc[ct] = __builtin_amdgcn_mfma_f32_16x16x32_bf16(af, bfr, acc[ct], 0, 0, 0);
            }
            __syncthreads();
        }
        // epilogue: C/D mapping col=lane&15, row=(lane>>4)*4+reg (m89-verified)
        float* pout = part + (size_t)ks * NN * NHID;
        const int orow = m0 + w * 16 + ((l >> 4) << 2);
        const int ocol = l & 15;
        #pragma unroll
        for (int ct = 0; ct < 4; ++ct)
            #pragma unroll
            for (int rix = 0; rix < 4; ++rix)
                pout[(size_t)(orow + rix) * 64 + ct * 16 + ocol] = acc[ct][rix];
    } else {
        // ----------------- build role: 1 row per block, 4-wave scan --------
        const int wave = t >> 6;
        const int lane = t & 63;
        const int row  = q9 * 8 + (r9 - 1);   // 0..8191

        const f32x4* arow4 = (const f32x4*)(adj + (size_t)row * NN);
        const long tb = (long)row * (row + 1) / 2;
        const unsigned long long lt = (1ull << lane) - 1ull;
        const size_t rowCAP = (size_t)row * CAP;
        const int qb = wave * 512;            // f32x4 index base of this quarter

        int base = 0;

        // scan quarter: 8 x 1KB wave loads, rolling prefetch, 32 ballots
        f32x4 buf[4];
        #pragma unroll
        for (int i = 0; i < 4; ++i)
            buf[i] = arow4[qb + i * 64 + lane];

        #pragma unroll
        for (int sb = 0; sb < 2; ++sb) {
            f32x4 cur[4];
            #pragma unroll
            for (int i = 0; i < 4; ++i) cur[i] = buf[i];
            if (sb == 0) {
                #pragma unroll
                for (int i = 0; i < 4; ++i)
                    buf[i] = arow4[qb + (4 + i) * 64 + lane];
            }
            #pragma unroll
            for (int i = 0; i < 4; ++i) {
                const int jb = (qb + (sb * 4 + i) * 64 + lane) * 4;
                #pragma unroll
                for (int s = 0; s < 4; ++s) {
                    bool nz = (cur[i][s] != 0.f);
                    unsigned long long mask = __ballot(nz);
                    if (nz) {
                        int pos = base + __popcll(mask & lt);
                        if (pos < QCAP) sm.bl.qbuf[wave][pos] = jb + s;
                    }
                    base += __popcll(mask);
                }
            }
        }
        if (lane == 0) sm.bl.qcnt[wave] = (base < QCAP) ? base : QCAP;
        __syncthreads();

        // stitch offsets
        int off = 0, ctot = 0;
        #pragma unroll
        for (int ww = 0; ww < 4; ++ww) {
            int qc = sm.bl.qcnt[ww];
            if (ww < wave) off += qc;
            ctot += qc;
        }
        if (ctot > CAP) ctot = CAP;

        // lane-parallel P gather + sigmoid + coalesced cols/vals write
        const int myq = sm.bl.qcnt[wave];
        float dsum = 0.f;
        if (lane < myq) {
            int j = sm.bl.qbuf[wave][lane];
            long pidx = (j <= row) ? (tb + j) : ((long)j * (j + 1) / 2 + row);
            float p = P[pidx];
            float v = 1.f / (1.f + __expf(-p));
            int pos = off + lane;
            if (pos < CAP) {
                cols[rowCAP + pos] = j;
                vals[rowCAP + pos] = v;
            }
            dsum = v;
        }
        #pragma unroll
        for (int s = 32; s; s >>= 1) dsum += __shfl_xor(dsum, s, 64);
        if (lane == 0) sm.bl.dpart[wave] = dsum;
        __syncthreads();
        if (t == 0) {
            float ds = sm.bl.dpart[0] + sm.bl.dpart[1] + sm.bl.dpart[2] + sm.bl.dpart[3];
            cnt[row]  = ctot;
            dinv[row] = 1.f / sqrtf(1.f + ds);
        }
    }
}

// ---------------------------------------------------------------------------
// Reduce the 8 K-split partials into XW1 (float4, fully coalesced).
// ---------------------------------------------------------------------------
__global__ __launch_bounds__(256) void k_reduce(const float* __restrict__ part,
                                                float* __restrict__ XW1) {
    const size_t i4 = (size_t)blockIdx.x * 256 + threadIdx.x;
    const f32x4* p4 = (const f32x4*)part;
    f32x4 s = p4[i4];
    #pragma unroll
    for (int ks = 1; ks < KSPLIT; ++ks)
        s += p4[(size_t)ks * (NN * NHID / 4) + i4];
    ((f32x4*)XW1)[i4] = s;
}

// ---------------------------------------------------------------------------
// spmm1: h1 = relu(dinv_i*(dinv_i*XW1_i + sum_j v*dinv_j*XW1_j) + b1),
// fused HW2 = h1 @ W2. One wave per row; depth-2 value pipeline.
// ---------------------------------------------------------------------------
__global__ __launch_bounds__(256) void k_spmm1(const float* __restrict__ XW1,
                                               const float* __restrict__ dinv,
                                               const int* __restrict__ cnt,
                                               const int* __restrict__ cols,
                                               const float* __restrict__ vals,
                                               const float* __restrict__ b1,
                                               const float* __restrict__ W2,
                                               float* __restrict__ HW2) {
    const int wave = threadIdx.x >> 6;
    const int lane = threadIdx.x & 63;
    const int row  = blockIdx.x * 4 + wave;
    if (row >= NN) return;

    const float di = dinv[row];
    float acc = di * XW1[(size_t)row * NHID + lane];
    const int c = cnt[row];
    const int*   cp = cols + (size_t)row * CAP;
    const float* vp = vals + (size_t)row * CAP;

    int j0 = 0, j1 = 0; float v0 = 0.f, v1 = 0.f, w0 = 0.f, w1 = 0.f, d0 = 0.f, d1 = 0.f;
    if (c > 0) { j0 = cp[0]; v0 = vp[0]; w0 = XW1[(size_t)j0 * NHID + lane]; d0 = dinv[j0]; }
    if (c > 1) { j1 = cp[1]; v1 = vp[1]; w1 = XW1[(size_t)j1 * NHID + lane]; d1 = dinv[j1]; }
    for (int k = 0; k < c; ++k) {
        acc += v0 * d0 * w0;
        j0 = j1; v0 = v1; w0 = w1; d0 = d1;
        if (k + 2 < c) {
            int jn = cp[k + 2];
            j1 = jn; v1 = vp[k + 2];
            w1 = XW1[(size_t)jn * NHID + lane];
            d1 = dinv[jn];
        }
    }
    float h1 = di * acc + b1[lane];
    h1 = fmaxf(h1, 0.f);

    float o[NCLASS];
    #pragma unroll
    for (int cc = 0; cc < NCLASS; ++cc) o[cc] = h1 * W2[lane * NCLASS + cc];
    #pragma unroll
    for (int cc = 0; cc < NCLASS; ++cc)
        for (int s = 32; s; s >>= 1) o[cc] += __shfl_xor(o[cc], s, 64);
    if (lane == 0) {
        #pragma unroll
        for (int cc = 0; cc < NCLASS; ++cc)
            HW2[(size_t)row * NCLASS + cc] = o[cc];
    }
}

// ---------------------------------------------------------------------------
// spmm2: h2 = norm_adj @ HW2 + b2 -> log_softmax. One wave per row.
// ---------------------------------------------------------------------------
__global__ __launch_bounds__(256) void k_spmm2(const float* __restrict__ HW2,
                                               const float* __restrict__ dinv,
                                               const int* __restrict__ cnt,
                                               const int* __restrict__ cols,
                                               const float* __restrict__ vals,
                                               const float* __restrict__ b2,
                                               float* __restrict__ out) {
    const int wave = threadIdx.x >> 6;
    const int lane = threadIdx.x & 63;
    const int row  = blockIdx.x * 4 + wave;
    if (row >= NN) return;

    const int c = cnt[row];
    const int*   cp = cols + (size_t)row * CAP;
    const float* vp = vals + (size_t)row * CAP;
    float acc[NCLASS] = {};
    for (int k = lane; k < c; k += 64) {
        int j   = cp[k];
        float wgt = vp[k] * dinv[j];
        #pragma unroll
        for (int cc = 0; cc < NCLASS; ++cc)
            acc[cc] += wgt * HW2[(size_t)j * NCLASS + cc];
    }
    #pragma unroll
    for (int cc = 0; cc < NCLASS; ++cc)
        for (int s = 32; s; s >>= 1) acc[cc] += __shfl_xor(acc[cc], s, 64);

    if (lane == 0) {
        const float di = dinv[row];
        float h[NCLASS], m = -1e30f;
        #pragma unroll
        for (int cc = 0; cc < NCLASS; ++cc) {
            h[cc] = di * (acc[cc] + di * HW2[(size_t)row * NCLASS + cc]) + b2[cc];
            m = fmaxf(m, h[cc]);
        }
        float s = 0.f;
        #pragma unroll
        for (int cc = 0; cc < NCLASS; ++cc) s += expf(h[cc] - m);
        float lse = m + logf(s);
        #pragma unroll
        for (int cc = 0; cc < NCLASS; ++cc)
            out[(size_t)row * NCLASS + cc] = h[cc] - lse;
    }
}

// ---------------------------------------------------------------------------
extern "C" void kernel_launch(void* const* d_in, const int* in_sizes, int n_in,
                              void* d_out, int out_size, void* d_ws, size_t ws_size,
                              hipStream_t stream) {
    const float* x   = (const float*)d_in[0];
    const float* adj = (const float*)d_in[1];
    const float* P   = (const float*)d_in[2];
    const float* W1  = (const float*)d_in[3];
    const float* b1  = (const float*)d_in[4];
    const float* W2  = (const float*)d_in[5];
    const float* b2  = (const float*)d_in[6];
    float* out = (float*)d_out;

    char* ws = (char*)d_ws;
    size_t off = 0;
    float* dinv = (float*)(ws + off);  off += (size_t)NN * 4;
    int*   cnt  = (int*)  (ws + off);  off += (size_t)NN * 4;
    int*   cols = (int*)  (ws + off);  off += (size_t)NN * CAP * 4;
    float* vals = (float*)(ws + off);  off += (size_t)NN * CAP * 4;
    float* XW1  = (float*)(ws + off);  off += (size_t)NN * NHID * 4;
    float* HW2  = (float*)(ws + off);  off += (size_t)NN * NCLASS * 4;
    float* part = (float*)(ws + off);  off += (size_t)KSPLIT * NN * NHID * 4;

    k_fused<<<dim3(NB_GEMM + NB_BUILD), dim3(256), 0, stream>>>(adj, P, x, W1,
                                                                dinv, cnt, cols, vals, part);
    k_reduce<<<dim3(NN * NHID / 4 / 256), dim3(256), 0, stream>>>(part, XW1);
    k_spmm1<<<dim3(NN / 4), dim3(256), 0, stream>>>(XW1, dinv, cnt, cols, vals, b1, W2, HW2);
    k_spmm2<<<dim3(NN / 4), dim3(256), 0, stream>>>(HW2, dinv, cnt, cols, vals, b2, out);
}